// Round 4
// baseline (165.246 us; speedup 1.0000x reference)
//
#include <hip/hip_runtime.h>

#define N_NODES 50000
#define N_EDGES 800000
#define SCAN_NB 49   // ceil(50000 / 1024) blocks, 1024 elements per block

typedef __attribute__((ext_vector_type(4))) _Float16 half4;
typedef __attribute__((ext_vector_type(8))) _Float16 half8;

// Recover in-degree from GCN norm: norm = max(deg,1)^-0.5 (fp32).
// deg=0 reconstructs as 1 (harmless over-allocation; aggregate uses the
// post-fill cursor as end pointer, so phantom slots are never read).
__device__ __forceinline__ int deg_from_norm(float n)
{
    return __float2int_rn(1.0f / (n * n));
}

// -------- Kernel A: t = fp16( (h @ W) * norm ) ----------------------------
// 32 rows/block, 4x4 per-thread tile. VGPR demand ~90 -> (256,4) caps at 128
// with no spill (round 2 spilled because demand was 156 vs forced cap; round
// 3 ran 156 VGPR -> 2 waves/SIMD, latency-bound at VALUBusy 23%).
// LDS = 16 KB (W chunk) + 4.6 KB (H tile) -> ~6 blocks/CU alongside 4 w/SIMD.
__global__ __launch_bounds__(256, 4) void gemm_scale_kernel(
    const float* __restrict__ h, const float* __restrict__ norm,
    const float* __restrict__ W, _Float16* __restrict__ t)
{
    __shared__ float Ws[32 * 128];    // [k][c] chunk, 16 KB
    __shared__ float Hs[32 * 36];     // [r][k] chunk, padded stride 36, 4.6 KB
    const int tid = threadIdx.x;
    const int rbase = blockIdx.x * 32;

    const int rt = tid >> 5, ct = tid & 31;
    const int r0 = rt * 4, c0 = ct * 4;
    float acc[4][4];
#pragma unroll
    for (int i = 0; i < 4; ++i)
#pragma unroll
        for (int j = 0; j < 4; ++j) acc[i][j] = 0.f;

    for (int kc = 0; kc < 128; kc += 32) {
        // stage W[kc..kc+31][:] : contiguous 16 KB, 4 float4/thread
        const float4* Wg = (const float4*)(W + (size_t)kc * 128);
        float4* Ws4 = (float4*)Ws;
#pragma unroll
        for (int i = 0; i < 4; ++i)
            Ws4[i * 256 + tid] = Wg[i * 256 + tid];
        // stage H[rbase..rbase+31][kc..kc+31] : 1 float4/thread
        {
            int row = tid >> 3;           // 0..31
            int c4 = (tid & 7) << 2;      // 0..28
            int gr = rbase + row;
            float4 v = make_float4(0.f, 0.f, 0.f, 0.f);
            if (gr < N_NODES) v = *(const float4*)(h + (size_t)gr * 128 + kc + c4);
            *(float4*)(Hs + row * 36 + c4) = v;
        }
        __syncthreads();

#pragma unroll
        for (int k = 0; k < 32; k += 4) {
            float4 w0 = *(const float4*)(Ws + (k + 0) * 128 + c0);
            float4 w1 = *(const float4*)(Ws + (k + 1) * 128 + c0);
            float4 w2 = *(const float4*)(Ws + (k + 2) * 128 + c0);
            float4 w3 = *(const float4*)(Ws + (k + 3) * 128 + c0);
#pragma unroll
            for (int i = 0; i < 4; ++i) {
                float4 hv = *(const float4*)(Hs + (r0 + i) * 36 + k);
                acc[i][0] += hv.x * w0.x + hv.y * w1.x + hv.z * w2.x + hv.w * w3.x;
                acc[i][1] += hv.x * w0.y + hv.y * w1.y + hv.z * w2.y + hv.w * w3.y;
                acc[i][2] += hv.x * w0.z + hv.y * w1.z + hv.z * w2.z + hv.w * w3.z;
                acc[i][3] += hv.x * w0.w + hv.y * w1.w + hv.z * w2.w + hv.w * w3.w;
            }
        }
        __syncthreads();
    }

#pragma unroll
    for (int i = 0; i < 4; ++i) {
        int gr = rbase + r0 + i;
        if (gr < N_NODES) {
            float nv = norm[gr];
            half4 v;
            v.x = (_Float16)(acc[i][0] * nv);
            v.y = (_Float16)(acc[i][1] * nv);
            v.z = (_Float16)(acc[i][2] * nv);
            v.w = (_Float16)(acc[i][3] * nv);
            *(half4*)(t + (size_t)gr * 128 + c0) = v;
        }
    }
}

// -------- CSR build step 1: per-block degree sums (from norm) -------------
__global__ __launch_bounds__(256) void scan_sums_kernel(
    const float* __restrict__ norm, int* __restrict__ bsum)
{
    const int tid = threadIdx.x;
    const int idx = blockIdx.x * 1024 + tid * 4;
    int s = 0;
    if (idx < N_NODES) {                 // 50000 % 4 == 0: group fully in-range
        float4 n = *(const float4*)(norm + idx);
        s = deg_from_norm(n.x) + deg_from_norm(n.y) +
            deg_from_norm(n.z) + deg_from_norm(n.w);
    }
#pragma unroll
    for (int d = 32; d > 0; d >>= 1) s += __shfl_down(s, d);
    __shared__ int ws[4];
    if ((tid & 63) == 0) ws[tid >> 6] = s;
    __syncthreads();
    if (tid == 0) bsum[blockIdx.x] = ws[0] + ws[1] + ws[2] + ws[3];
}

// -------- CSR build step 2: exclusive scan of 49 block sums (1 wave) ------
__global__ __launch_bounds__(64) void scan_bsum_kernel(
    const int* __restrict__ bsum, int* __restrict__ boff)
{
    const int tid = threadIdx.x;
    int v = (tid < SCAN_NB) ? bsum[tid] : 0;
    int inc = v;
#pragma unroll
    for (int d = 1; d < 64; d <<= 1) {
        int u = __shfl_up(inc, d);
        if (tid >= d) inc += u;
    }
    if (tid < SCAN_NB) boff[tid] = inc - v;   // exclusive prefix
}

// -------- CSR build step 3: block-local scan + write off/cur --------------
__global__ __launch_bounds__(256) void scan_write_kernel(
    const float* __restrict__ norm, const int* __restrict__ boff,
    int* __restrict__ off, int* __restrict__ cur)
{
    const int tid = threadIdx.x;
    const int idx = blockIdx.x * 1024 + tid * 4;

    int4 v = make_int4(0, 0, 0, 0);
    if (idx < N_NODES) {
        float4 n = *(const float4*)(norm + idx);
        v.x = deg_from_norm(n.x); v.y = deg_from_norm(n.y);
        v.z = deg_from_norm(n.z); v.w = deg_from_norm(n.w);
    }
    const int s = v.x + v.y + v.z + v.w;

    const int lane = tid & 63, w = tid >> 6;
    int inc = s;
#pragma unroll
    for (int d = 1; d < 64; d <<= 1) {
        int u = __shfl_up(inc, d);
        if (lane >= d) inc += u;
    }
    __shared__ int wsum[4];
    if (lane == 63) wsum[w] = inc;
    __syncthreads();
    int woff = 0;
    for (int i = 0; i < w; ++i) woff += wsum[i];

    int o0 = boff[blockIdx.x] + woff + inc - s;
    int o1 = o0 + v.x;
    int o2 = o1 + v.y;
    int o3 = o2 + v.z;

    if (idx < N_NODES) {
        int4 ov = make_int4(o0, o1, o2, o3);
        *(int4*)(off + idx) = ov;
        *(int4*)(cur + idx) = ov;
    }
}

// -------- CSR build step 4: fill edge-source lists ------------------------
__global__ __launch_bounds__(256) void fill_kernel(
    const int* __restrict__ src, const int* __restrict__ dst,
    int* __restrict__ cur, int* __restrict__ esrc)
{
    int e = blockIdx.x * blockDim.x + threadIdx.x;
    if (e < N_EDGES) {
        int p = atomicAdd(&cur[dst[e]], 1);
        esrc[p] = src[e];
    }
}

// -------- Kernel D: gather-aggregate (fp16 t) + fused finalize ------------
// 16 lanes per dst node; lane l owns halfs [8l..8l+7] (16 B load per edge).
// End pointer is cur[g] (post-fill), so phantom slots of deg-0 nodes are
// never read.
__global__ __launch_bounds__(256) void aggregate_kernel(
    const int* __restrict__ off, const int* __restrict__ cur,
    const int* __restrict__ esrc, const _Float16* __restrict__ t,
    const float* __restrict__ norm, const float* __restrict__ b,
    float* __restrict__ out)
{
    const int g = blockIdx.x * 16 + (threadIdx.x >> 4);
    if (g >= N_NODES) return;
    const int l = threadIdx.x & 15;
    const int c = l << 3;
    const int i0 = off[g], i1 = cur[g];

    float acc[8];
#pragma unroll
    for (int j = 0; j < 8; ++j) acc[j] = 0.f;

    for (int i = i0; i < i1; ++i) {
        int s = esrc[i];
        half8 v = *(const half8*)(t + (size_t)s * 128 + c);
#pragma unroll
        for (int j = 0; j < 8; ++j) acc[j] += (float)v[j];
    }

    const float nv = norm[g];
    const float4 b0 = *(const float4*)(b + c);
    const float4 b1 = *(const float4*)(b + c + 4);
    float4 o0 = make_float4(acc[0] * nv + b0.x, acc[1] * nv + b0.y,
                            acc[2] * nv + b0.z, acc[3] * nv + b0.w);
    float4 o1 = make_float4(acc[4] * nv + b1.x, acc[5] * nv + b1.y,
                            acc[6] * nv + b1.z, acc[7] * nv + b1.w);
    *(float4*)(out + (size_t)g * 128 + c) = o0;
    *(float4*)(out + (size_t)g * 128 + c + 4) = o1;
}

static inline size_t align256(size_t x) { return (x + 255) & ~(size_t)255; }

extern "C" void kernel_launch(void* const* d_in, const int* in_sizes, int n_in,
                              void* d_out, int out_size, void* d_ws, size_t ws_size,
                              hipStream_t stream)
{
    const float* h    = (const float*)d_in[0];
    const float* norm = (const float*)d_in[1];
    const float* W    = (const float*)d_in[2];
    const float* b    = (const float*)d_in[3];
    const int*   src  = (const int*)d_in[4];
    const int*   dst  = (const int*)d_in[5];
    float* out = (float*)d_out;

    // workspace layout
    char* ws = (char*)d_ws;
    size_t o = 0;
    _Float16* t = (_Float16*)(ws + o);  o = align256(o + (size_t)N_NODES * 128 * 2);
    int* off = (int*)(ws + o);          o = align256(o + (size_t)N_NODES * 4);
    int* cur = (int*)(ws + o);          o = align256(o + (size_t)N_NODES * 4);
    int* esrc = (int*)(ws + o);         o = align256(o + ((size_t)N_EDGES + 1024) * 4);
    int* bsum = (int*)(ws + o);         o = align256(o + (size_t)SCAN_NB * 4);
    int* boff = (int*)(ws + o);         o = align256(o + (size_t)SCAN_NB * 4);

    gemm_scale_kernel<<<(N_NODES + 31) / 32, 256, 0, stream>>>(h, norm, W, t);
    scan_sums_kernel<<<SCAN_NB, 256, 0, stream>>>(norm, bsum);
    scan_bsum_kernel<<<1, 64, 0, stream>>>(bsum, boff);
    scan_write_kernel<<<SCAN_NB, 256, 0, stream>>>(norm, boff, off, cur);
    fill_kernel<<<(N_EDGES + 255) / 256, 256, 0, stream>>>(src, dst, cur, esrc);
    aggregate_kernel<<<(N_NODES + 15) / 16, 256, 0, stream>>>(off, cur, esrc, t, norm, b, out);
}

// Round 5
// 133.392 us; speedup vs baseline: 1.2388x; 1.2388x over previous
//
#include <hip/hip_runtime.h>

#define N_NODES 50000
#define N_EDGES 800000
#define SCAN_NB 49   // ceil(50000 / 1024) blocks, 1024 elements per block

typedef __attribute__((ext_vector_type(4))) _Float16 half4;
typedef __attribute__((ext_vector_type(8))) _Float16 half8;

// Recover in-degree from GCN norm: norm = max(deg,1)^-0.5 (fp32).
// deg=0 reconstructs as 1 (harmless over-allocation; aggregate uses the
// post-fill cursor as end pointer, so phantom slots are never read).
__device__ __forceinline__ int deg_from_norm(float n)
{
    return __float2int_rn(1.0f / (n * n));
}

// -------- Kernel A: t = fp16( (h @ W) * norm ) ----------------------------
// 32 rows/block, 4x4 per-thread tile, plain __launch_bounds__(256).
// SESSION RULE (rounds 2 & 4): a min-waves clause on this kernel makes the
// allocator collapse VGPRs (156->64) and spill the accumulators to scratch
// (WRITE_SIZE 12.5 MB -> 183-564 MB). Natural demand for the 4x4 tile is
// ~100 VGPR, which sits under the 128 occupancy step on its own.
__global__ __launch_bounds__(256) void gemm_scale_kernel(
    const float* __restrict__ h, const float* __restrict__ norm,
    const float* __restrict__ W, _Float16* __restrict__ t)
{
    __shared__ float Ws[32 * 128];    // [k][c] chunk, 16 KB
    __shared__ float Hs[32 * 36];     // [r][k] chunk, padded stride 36, 4.6 KB
    const int tid = threadIdx.x;
    const int rbase = blockIdx.x * 32;

    const int rt = tid >> 5, ct = tid & 31;
    const int r0 = rt * 4, c0 = ct * 4;
    float acc[4][4];
#pragma unroll
    for (int i = 0; i < 4; ++i)
#pragma unroll
        for (int j = 0; j < 4; ++j) acc[i][j] = 0.f;

    for (int kc = 0; kc < 128; kc += 32) {
        // stage W[kc..kc+31][:] : contiguous 16 KB, 4 float4/thread
        const float4* Wg = (const float4*)(W + (size_t)kc * 128);
        float4* Ws4 = (float4*)Ws;
#pragma unroll
        for (int i = 0; i < 4; ++i)
            Ws4[i * 256 + tid] = Wg[i * 256 + tid];
        // stage H[rbase..rbase+31][kc..kc+31] : 1 float4/thread
        {
            int row = tid >> 3;           // 0..31
            int c4 = (tid & 7) << 2;      // 0..28
            int gr = rbase + row;
            float4 v = make_float4(0.f, 0.f, 0.f, 0.f);
            if (gr < N_NODES) v = *(const float4*)(h + (size_t)gr * 128 + kc + c4);
            *(float4*)(Hs + row * 36 + c4) = v;
        }
        __syncthreads();

#pragma unroll
        for (int k = 0; k < 32; k += 4) {
            float4 w0 = *(const float4*)(Ws + (k + 0) * 128 + c0);
            float4 w1 = *(const float4*)(Ws + (k + 1) * 128 + c0);
            float4 w2 = *(const float4*)(Ws + (k + 2) * 128 + c0);
            float4 w3 = *(const float4*)(Ws + (k + 3) * 128 + c0);
#pragma unroll
            for (int i = 0; i < 4; ++i) {
                float4 hv = *(const float4*)(Hs + (r0 + i) * 36 + k);
                acc[i][0] += hv.x * w0.x + hv.y * w1.x + hv.z * w2.x + hv.w * w3.x;
                acc[i][1] += hv.x * w0.y + hv.y * w1.y + hv.z * w2.y + hv.w * w3.y;
                acc[i][2] += hv.x * w0.z + hv.y * w1.z + hv.z * w2.z + hv.w * w3.z;
                acc[i][3] += hv.x * w0.w + hv.y * w1.w + hv.z * w2.w + hv.w * w3.w;
            }
        }
        __syncthreads();
    }

#pragma unroll
    for (int i = 0; i < 4; ++i) {
        int gr = rbase + r0 + i;
        if (gr < N_NODES) {
            float nv = norm[gr];
            half4 v;
            v.x = (_Float16)(acc[i][0] * nv);
            v.y = (_Float16)(acc[i][1] * nv);
            v.z = (_Float16)(acc[i][2] * nv);
            v.w = (_Float16)(acc[i][3] * nv);
            *(half4*)(t + (size_t)gr * 128 + c0) = v;
        }
    }
}

// -------- CSR build step 1: per-block degree sums (from norm) -------------
__global__ __launch_bounds__(256) void scan_sums_kernel(
    const float* __restrict__ norm, int* __restrict__ bsum)
{
    const int tid = threadIdx.x;
    const int idx = blockIdx.x * 1024 + tid * 4;
    int s = 0;
    if (idx < N_NODES) {                 // 50000 % 4 == 0: group fully in-range
        float4 n = *(const float4*)(norm + idx);
        s = deg_from_norm(n.x) + deg_from_norm(n.y) +
            deg_from_norm(n.z) + deg_from_norm(n.w);
    }
#pragma unroll
    for (int d = 32; d > 0; d >>= 1) s += __shfl_down(s, d);
    __shared__ int ws[4];
    if ((tid & 63) == 0) ws[tid >> 6] = s;
    __syncthreads();
    if (tid == 0) bsum[blockIdx.x] = ws[0] + ws[1] + ws[2] + ws[3];
}

// -------- CSR build step 2: exclusive scan of 49 block sums (1 wave) ------
__global__ __launch_bounds__(64) void scan_bsum_kernel(
    const int* __restrict__ bsum, int* __restrict__ boff)
{
    const int tid = threadIdx.x;
    int v = (tid < SCAN_NB) ? bsum[tid] : 0;
    int inc = v;
#pragma unroll
    for (int d = 1; d < 64; d <<= 1) {
        int u = __shfl_up(inc, d);
        if (tid >= d) inc += u;
    }
    if (tid < SCAN_NB) boff[tid] = inc - v;   // exclusive prefix
}

// -------- CSR build step 3: block-local scan + write off/cur --------------
__global__ __launch_bounds__(256) void scan_write_kernel(
    const float* __restrict__ norm, const int* __restrict__ boff,
    int* __restrict__ off, int* __restrict__ cur)
{
    const int tid = threadIdx.x;
    const int idx = blockIdx.x * 1024 + tid * 4;

    int4 v = make_int4(0, 0, 0, 0);
    if (idx < N_NODES) {
        float4 n = *(const float4*)(norm + idx);
        v.x = deg_from_norm(n.x); v.y = deg_from_norm(n.y);
        v.z = deg_from_norm(n.z); v.w = deg_from_norm(n.w);
    }
    const int s = v.x + v.y + v.z + v.w;

    const int lane = tid & 63, w = tid >> 6;
    int inc = s;
#pragma unroll
    for (int d = 1; d < 64; d <<= 1) {
        int u = __shfl_up(inc, d);
        if (lane >= d) inc += u;
    }
    __shared__ int wsum[4];
    if (lane == 63) wsum[w] = inc;
    __syncthreads();
    int woff = 0;
    for (int i = 0; i < w; ++i) woff += wsum[i];

    int o0 = boff[blockIdx.x] + woff + inc - s;
    int o1 = o0 + v.x;
    int o2 = o1 + v.y;
    int o3 = o2 + v.z;

    if (idx < N_NODES) {
        int4 ov = make_int4(o0, o1, o2, o3);
        *(int4*)(off + idx) = ov;
        *(int4*)(cur + idx) = ov;
    }
}

// -------- CSR build step 4: fill edge-source lists ------------------------
__global__ __launch_bounds__(256) void fill_kernel(
    const int* __restrict__ src, const int* __restrict__ dst,
    int* __restrict__ cur, int* __restrict__ esrc)
{
    int e = blockIdx.x * blockDim.x + threadIdx.x;
    if (e < N_EDGES) {
        int p = atomicAdd(&cur[dst[e]], 1);
        esrc[p] = src[e];
    }
}

// -------- Kernel D: gather-aggregate (fp16 t) + fused finalize ------------
// 16 lanes per dst node; lane l owns halfs [8l..8l+7] (16 B load per edge).
// End pointer is cur[g] (post-fill), so phantom slots of deg-0 nodes are
// never read.
__global__ __launch_bounds__(256) void aggregate_kernel(
    const int* __restrict__ off, const int* __restrict__ cur,
    const int* __restrict__ esrc, const _Float16* __restrict__ t,
    const float* __restrict__ norm, const float* __restrict__ b,
    float* __restrict__ out)
{
    const int g = blockIdx.x * 16 + (threadIdx.x >> 4);
    if (g >= N_NODES) return;
    const int l = threadIdx.x & 15;
    const int c = l << 3;
    const int i0 = off[g], i1 = cur[g];

    float acc[8];
#pragma unroll
    for (int j = 0; j < 8; ++j) acc[j] = 0.f;

    for (int i = i0; i < i1; ++i) {
        int s = esrc[i];
        half8 v = *(const half8*)(t + (size_t)s * 128 + c);
#pragma unroll
        for (int j = 0; j < 8; ++j) acc[j] += (float)v[j];
    }

    const float nv = norm[g];
    const float4 b0 = *(const float4*)(b + c);
    const float4 b1 = *(const float4*)(b + c + 4);
    float4 o0 = make_float4(acc[0] * nv + b0.x, acc[1] * nv + b0.y,
                            acc[2] * nv + b0.z, acc[3] * nv + b0.w);
    float4 o1 = make_float4(acc[4] * nv + b1.x, acc[5] * nv + b1.y,
                            acc[6] * nv + b1.z, acc[7] * nv + b1.w);
    *(float4*)(out + (size_t)g * 128 + c) = o0;
    *(float4*)(out + (size_t)g * 128 + c + 4) = o1;
}

static inline size_t align256(size_t x) { return (x + 255) & ~(size_t)255; }

extern "C" void kernel_launch(void* const* d_in, const int* in_sizes, int n_in,
                              void* d_out, int out_size, void* d_ws, size_t ws_size,
                              hipStream_t stream)
{
    const float* h    = (const float*)d_in[0];
    const float* norm = (const float*)d_in[1];
    const float* W    = (const float*)d_in[2];
    const float* b    = (const float*)d_in[3];
    const int*   src  = (const int*)d_in[4];
    const int*   dst  = (const int*)d_in[5];
    float* out = (float*)d_out;

    // workspace layout
    char* ws = (char*)d_ws;
    size_t o = 0;
    _Float16* t = (_Float16*)(ws + o);  o = align256(o + (size_t)N_NODES * 128 * 2);
    int* off = (int*)(ws + o);          o = align256(o + (size_t)N_NODES * 4);
    int* cur = (int*)(ws + o);          o = align256(o + (size_t)N_NODES * 4);
    int* esrc = (int*)(ws + o);         o = align256(o + ((size_t)N_EDGES + 1024) * 4);
    int* bsum = (int*)(ws + o);         o = align256(o + (size_t)SCAN_NB * 4);
    int* boff = (int*)(ws + o);         o = align256(o + (size_t)SCAN_NB * 4);

    gemm_scale_kernel<<<(N_NODES + 31) / 32, 256, 0, stream>>>(h, norm, W, t);
    scan_sums_kernel<<<SCAN_NB, 256, 0, stream>>>(norm, bsum);
    scan_bsum_kernel<<<1, 64, 0, stream>>>(bsum, boff);
    scan_write_kernel<<<SCAN_NB, 256, 0, stream>>>(norm, boff, off, cur);
    fill_kernel<<<(N_EDGES + 255) / 256, 256, 0, stream>>>(src, dst, cur, esrc);
    aggregate_kernel<<<(N_NODES + 15) / 16, 256, 0, stream>>>(off, cur, esrc, t, norm, b, out);
}

// Round 6
// 97.994 us; speedup vs baseline: 1.6863x; 1.3612x over previous
//
#include <hip/hip_runtime.h>

#define N_NODES 50000
#define N_EDGES 800000
#define SCAN_NB 49        // ceil(50000 / 1024) blocks, 1024 elements per block
#define CUR_STRIDE 16     // pad cur to one counter per 64B line (atomic contention)

#define GEMM_NB ((N_NODES + 31) / 32)          // 1563 gemm tiles
#define FILL_NB ((N_EDGES + 255) / 256)        // 3125 fill chunks
#define FUSED_NB (GEMM_NB + FILL_NB)           // 4688 blocks: %3==0 -> gemm

typedef __attribute__((ext_vector_type(4))) _Float16 half4;
typedef __attribute__((ext_vector_type(8))) _Float16 half8;

// Recover in-degree from GCN norm: norm = max(deg,1)^-0.5 (fp32).
// deg=0 reconstructs as 1 (harmless over-allocation; aggregate uses the
// post-fill cursor as end pointer, so phantom slots are never read).
__device__ __forceinline__ int deg_from_norm(float n)
{
    return __float2int_rn(1.0f / (n * n));
}

// -------- Fused Kernel A: gemm_scale tiles + CSR fill, heterogeneous grid --
// Blocks with blockIdx.x % 3 == 0 compute one 32-row GEMM tile
// (t = fp16((h@W)*norm)); the other blocks each place 256 edges into esrc.
// The two phases are independent (fill needs only off/cur from the scans),
// so overlapping the compute-bound GEMM with the latency-bound atomic fill
// hides one under the other.
// SESSION RULE (rounds 2 & 4): no min-waves clause — it collapses VGPRs and
// spills the accumulators (WRITE_SIZE 12.5 MB -> 183-564 MB tripwire).
__global__ __launch_bounds__(256) void fused_gemm_fill_kernel(
    const float* __restrict__ h, const float* __restrict__ norm,
    const float* __restrict__ W, _Float16* __restrict__ t,
    const int* __restrict__ src, const int* __restrict__ dst,
    int* __restrict__ cur, int* __restrict__ esrc)
{
    __shared__ float Ws[32 * 128];    // [k][c] chunk, 16 KB
    __shared__ float Hs[32 * 36];     // [r][k] chunk, padded stride 36, 4.6 KB
    const int tid = threadIdx.x;
    const int bid = blockIdx.x;

    if (bid % 3 != 0) {
        // ---- fill role: 256 edges per block --------------------------------
        const int fid = bid - bid / 3 - 1;          // 0 .. FILL_NB-1
        const int e = fid * 256 + tid;
        if (e < N_EDGES) {
            int d = dst[e];
            int p = atomicAdd(&cur[(size_t)d * CUR_STRIDE], 1);
            esrc[p] = src[e];
        }
        return;
    }

    // ---- gemm role: one 32-row tile ---------------------------------------
    const int rbase = (bid / 3) * 32;

    const int rt = tid >> 5, ct = tid & 31;
    const int r0 = rt * 4, c0 = ct * 4;
    float acc[4][4];
#pragma unroll
    for (int i = 0; i < 4; ++i)
#pragma unroll
        for (int j = 0; j < 4; ++j) acc[i][j] = 0.f;

    for (int kc = 0; kc < 128; kc += 32) {
        // stage W[kc..kc+31][:] : contiguous 16 KB, 4 float4/thread
        const float4* Wg = (const float4*)(W + (size_t)kc * 128);
        float4* Ws4 = (float4*)Ws;
#pragma unroll
        for (int i = 0; i < 4; ++i)
            Ws4[i * 256 + tid] = Wg[i * 256 + tid];
        // stage H[rbase..rbase+31][kc..kc+31] : 1 float4/thread
        {
            int row = tid >> 3;           // 0..31
            int c4 = (tid & 7) << 2;      // 0..28
            int gr = rbase + row;
            float4 v = make_float4(0.f, 0.f, 0.f, 0.f);
            if (gr < N_NODES) v = *(const float4*)(h + (size_t)gr * 128 + kc + c4);
            *(float4*)(Hs + row * 36 + c4) = v;
        }
        __syncthreads();

#pragma unroll
        for (int k = 0; k < 32; k += 4) {
            float4 w0 = *(const float4*)(Ws + (k + 0) * 128 + c0);
            float4 w1 = *(const float4*)(Ws + (k + 1) * 128 + c0);
            float4 w2 = *(const float4*)(Ws + (k + 2) * 128 + c0);
            float4 w3 = *(const float4*)(Ws + (k + 3) * 128 + c0);
#pragma unroll
            for (int i = 0; i < 4; ++i) {
                float4 hv = *(const float4*)(Hs + (r0 + i) * 36 + k);
                acc[i][0] += hv.x * w0.x + hv.y * w1.x + hv.z * w2.x + hv.w * w3.x;
                acc[i][1] += hv.x * w0.y + hv.y * w1.y + hv.z * w2.y + hv.w * w3.y;
                acc[i][2] += hv.x * w0.z + hv.y * w1.z + hv.z * w2.z + hv.w * w3.z;
                acc[i][3] += hv.x * w0.w + hv.y * w1.w + hv.z * w2.w + hv.w * w3.w;
            }
        }
        __syncthreads();
    }

#pragma unroll
    for (int i = 0; i < 4; ++i) {
        int gr = rbase + r0 + i;
        if (gr < N_NODES) {
            float nv = norm[gr];
            half4 v;
            v.x = (_Float16)(acc[i][0] * nv);
            v.y = (_Float16)(acc[i][1] * nv);
            v.z = (_Float16)(acc[i][2] * nv);
            v.w = (_Float16)(acc[i][3] * nv);
            *(half4*)(t + (size_t)gr * 128 + c0) = v;
        }
    }
}

// -------- CSR build step 1: per-block degree sums (from norm) -------------
__global__ __launch_bounds__(256) void scan_sums_kernel(
    const float* __restrict__ norm, int* __restrict__ bsum)
{
    const int tid = threadIdx.x;
    const int idx = blockIdx.x * 1024 + tid * 4;
    int s = 0;
    if (idx < N_NODES) {                 // 50000 % 4 == 0: group fully in-range
        float4 n = *(const float4*)(norm + idx);
        s = deg_from_norm(n.x) + deg_from_norm(n.y) +
            deg_from_norm(n.z) + deg_from_norm(n.w);
    }
#pragma unroll
    for (int d = 32; d > 0; d >>= 1) s += __shfl_down(s, d);
    __shared__ int ws[4];
    if ((tid & 63) == 0) ws[tid >> 6] = s;
    __syncthreads();
    if (tid == 0) bsum[blockIdx.x] = ws[0] + ws[1] + ws[2] + ws[3];
}

// -------- CSR build step 2: exclusive scan of 49 block sums (1 wave) ------
__global__ __launch_bounds__(64) void scan_bsum_kernel(
    const int* __restrict__ bsum, int* __restrict__ boff)
{
    const int tid = threadIdx.x;
    int v = (tid < SCAN_NB) ? bsum[tid] : 0;
    int inc = v;
#pragma unroll
    for (int d = 1; d < 64; d <<= 1) {
        int u = __shfl_up(inc, d);
        if (tid >= d) inc += u;
    }
    if (tid < SCAN_NB) boff[tid] = inc - v;   // exclusive prefix
}

// -------- CSR build step 3: block-local scan + write off/cur --------------
// cur is padded: one counter per 64B line (CUR_STRIDE ints per node).
__global__ __launch_bounds__(256) void scan_write_kernel(
    const float* __restrict__ norm, const int* __restrict__ boff,
    int* __restrict__ off, int* __restrict__ cur)
{
    const int tid = threadIdx.x;
    const int idx = blockIdx.x * 1024 + tid * 4;

    int4 v = make_int4(0, 0, 0, 0);
    if (idx < N_NODES) {
        float4 n = *(const float4*)(norm + idx);
        v.x = deg_from_norm(n.x); v.y = deg_from_norm(n.y);
        v.z = deg_from_norm(n.z); v.w = deg_from_norm(n.w);
    }
    const int s = v.x + v.y + v.z + v.w;

    const int lane = tid & 63, w = tid >> 6;
    int inc = s;
#pragma unroll
    for (int d = 1; d < 64; d <<= 1) {
        int u = __shfl_up(inc, d);
        if (lane >= d) inc += u;
    }
    __shared__ int wsum[4];
    if (lane == 63) wsum[w] = inc;
    __syncthreads();
    int woff = 0;
    for (int i = 0; i < w; ++i) woff += wsum[i];

    int o0 = boff[blockIdx.x] + woff + inc - s;
    int o1 = o0 + v.x;
    int o2 = o1 + v.y;
    int o3 = o2 + v.z;

    if (idx < N_NODES) {
        int4 ov = make_int4(o0, o1, o2, o3);
        *(int4*)(off + idx) = ov;
        cur[(size_t)(idx + 0) * CUR_STRIDE] = o0;
        cur[(size_t)(idx + 1) * CUR_STRIDE] = o1;
        cur[(size_t)(idx + 2) * CUR_STRIDE] = o2;
        cur[(size_t)(idx + 3) * CUR_STRIDE] = o3;
    }
}

// -------- Kernel D: gather-aggregate (fp16 t) + fused finalize ------------
// 16 lanes per dst node; lane l owns halfs [8l..8l+7] (16 B load per edge).
// End pointer is cur[g*CUR_STRIDE] (post-fill), so phantom slots of deg-0
// nodes are never read. Edge loop unrolled x2 for latency overlap.
__global__ __launch_bounds__(256) void aggregate_kernel(
    const int* __restrict__ off, const int* __restrict__ cur,
    const int* __restrict__ esrc, const _Float16* __restrict__ t,
    const float* __restrict__ norm, const float* __restrict__ b,
    float* __restrict__ out)
{
    const int g = blockIdx.x * 16 + (threadIdx.x >> 4);
    if (g >= N_NODES) return;
    const int l = threadIdx.x & 15;
    const int c = l << 3;
    const int i0 = off[g], i1 = cur[(size_t)g * CUR_STRIDE];

    float acc0[8], acc1[8];
#pragma unroll
    for (int j = 0; j < 8; ++j) { acc0[j] = 0.f; acc1[j] = 0.f; }

    int i = i0;
    for (; i + 2 <= i1; i += 2) {
        int s0 = esrc[i];
        int s1 = esrc[i + 1];
        half8 v0 = *(const half8*)(t + (size_t)s0 * 128 + c);
        half8 v1 = *(const half8*)(t + (size_t)s1 * 128 + c);
#pragma unroll
        for (int j = 0; j < 8; ++j) { acc0[j] += (float)v0[j]; acc1[j] += (float)v1[j]; }
    }
    if (i < i1) {
        int s0 = esrc[i];
        half8 v0 = *(const half8*)(t + (size_t)s0 * 128 + c);
#pragma unroll
        for (int j = 0; j < 8; ++j) acc0[j] += (float)v0[j];
    }

    const float nv = norm[g];
    const float4 b0 = *(const float4*)(b + c);
    const float4 b1 = *(const float4*)(b + c + 4);
    float4 o0 = make_float4((acc0[0] + acc1[0]) * nv + b0.x,
                            (acc0[1] + acc1[1]) * nv + b0.y,
                            (acc0[2] + acc1[2]) * nv + b0.z,
                            (acc0[3] + acc1[3]) * nv + b0.w);
    float4 o1 = make_float4((acc0[4] + acc1[4]) * nv + b1.x,
                            (acc0[5] + acc1[5]) * nv + b1.y,
                            (acc0[6] + acc1[6]) * nv + b1.z,
                            (acc0[7] + acc1[7]) * nv + b1.w);
    *(float4*)(out + (size_t)g * 128 + c) = o0;
    *(float4*)(out + (size_t)g * 128 + c + 4) = o1;
}

static inline size_t align256(size_t x) { return (x + 255) & ~(size_t)255; }

extern "C" void kernel_launch(void* const* d_in, const int* in_sizes, int n_in,
                              void* d_out, int out_size, void* d_ws, size_t ws_size,
                              hipStream_t stream)
{
    const float* h    = (const float*)d_in[0];
    const float* norm = (const float*)d_in[1];
    const float* W    = (const float*)d_in[2];
    const float* b    = (const float*)d_in[3];
    const int*   src  = (const int*)d_in[4];
    const int*   dst  = (const int*)d_in[5];
    float* out = (float*)d_out;

    // workspace layout
    char* ws = (char*)d_ws;
    size_t o = 0;
    _Float16* t = (_Float16*)(ws + o);  o = align256(o + (size_t)N_NODES * 128 * 2);
    int* off = (int*)(ws + o);          o = align256(o + (size_t)N_NODES * 4);
    int* cur = (int*)(ws + o);          o = align256(o + (size_t)N_NODES * CUR_STRIDE * 4);
    int* esrc = (int*)(ws + o);         o = align256(o + ((size_t)N_EDGES + 1024) * 4);
    int* bsum = (int*)(ws + o);         o = align256(o + (size_t)SCAN_NB * 4);
    int* boff = (int*)(ws + o);         o = align256(o + (size_t)SCAN_NB * 4);

    scan_sums_kernel<<<SCAN_NB, 256, 0, stream>>>(norm, bsum);
    scan_bsum_kernel<<<1, 64, 0, stream>>>(bsum, boff);
    scan_write_kernel<<<SCAN_NB, 256, 0, stream>>>(norm, boff, off, cur);
    fused_gemm_fill_kernel<<<FUSED_NB, 256, 0, stream>>>(h, norm, W, t,
                                                         src, dst, cur, esrc);
    aggregate_kernel<<<(N_NODES + 15) / 16, 256, 0, stream>>>(off, cur, esrc, t, norm, b, out);
}

// Round 7
// 91.655 us; speedup vs baseline: 1.8029x; 1.0692x over previous
//
#include <hip/hip_runtime.h>

#define N_NODES 50000
#define N_EDGES 800000
#define SCAN_NB 49        // ceil(50000 / 1024) blocks, 1024 elements per block

#define NBUCKETS 196      // ceil(50000/256): bucket = dst >> 8 (256 nodes each)
#define BIN_EDGES 4096    // edges per bin block
#define BIN_NB 196        // ceil(800000/4096)
#define BUCKET_CAP 5120   // slots per bucket (mean 4096, sd ~64 -> 16 sigma margin)

#define GEMM_NB ((N_NODES + 31) / 32)          // 1563 gemm tiles
#define FUSED_NB (BIN_NB * 9)                  // 1764: bid%9==8 -> bin role

typedef __attribute__((ext_vector_type(4))) _Float16 half4;
typedef __attribute__((ext_vector_type(8))) _Float16 half8;

// Recover in-degree from GCN norm: norm = max(deg,1)^-0.5 (fp32).
// deg=0 reconstructs as 1 (harmless over-allocation; aggregate uses the
// post-scatter cursor as end pointer, so phantom slots are never read).
__device__ __forceinline__ int deg_from_norm(float n)
{
    return __float2int_rn(1.0f / (n * n));
}

// -------- Fused Kernel A: gemm_scale tiles + edge binning (pass 1) --------
// Blocks with bid%9==8 bin 4096 edges into per-bucket sequential streams
// (bucket = dst>>8); the rest compute one 32-row GEMM tile each.
// Binning replaces the old fill's 800K contended global atomics + 16x
// line-amplified esrc scatter with: LDS histogram -> 1 global atomic per
// (block,bucket) -> sequential 8B pair writes per bucket stream.
// SESSION RULE (rounds 2 & 4): no min-waves clause — it collapses VGPRs and
// spills the accumulators (WRITE_SIZE tripwire 12.5 MB -> 183-564 MB).
__global__ __launch_bounds__(256) void fused_gemm_bin_kernel(
    const float* __restrict__ h, const float* __restrict__ norm,
    const float* __restrict__ W, _Float16* __restrict__ t,
    const int* __restrict__ src, const int* __restrict__ dst,
    int* __restrict__ bcur, int2* __restrict__ bucketbuf)
{
    const int tid = threadIdx.x;
    const int bid = blockIdx.x;

    if (bid % 9 == 8) {
        // ---- bin role: 4096 edges -> 196 bucket streams --------------------
        __shared__ int hist[NBUCKETS];
        const int bs = (bid / 9) * BIN_EDGES;
        for (int i = tid; i < NBUCKETS; i += 256) hist[i] = 0;
        __syncthreads();
        // histogram (dst only)
#pragma unroll
        for (int j = 0; j < 4; ++j) {
            int e4 = bs + (j * 256 + tid) * 4;
            if (e4 < N_EDGES) {               // 4096 & 1280 both %4==0
                int4 d4 = *(const int4*)(dst + e4);
                atomicAdd(&hist[d4.x >> 8], 1);
                atomicAdd(&hist[d4.y >> 8], 1);
                atomicAdd(&hist[d4.z >> 8], 1);
                atomicAdd(&hist[d4.w >> 8], 1);
            }
        }
        __syncthreads();
        int base = 0;
        if (tid < NBUCKETS) {
            int hc = hist[tid];
            if (hc) base = atomicAdd(&bcur[tid], hc);
        }
        __syncthreads();
        if (tid < NBUCKETS) hist[tid] = base;   // reuse as running cursor
        __syncthreads();
        // write pass: (src,dst) pairs into bucket streams
#pragma unroll
        for (int j = 0; j < 4; ++j) {
            int e4 = bs + (j * 256 + tid) * 4;
            if (e4 < N_EDGES) {
                int4 d4 = *(const int4*)(dst + e4);
                int4 s4 = *(const int4*)(src + e4);
                int b0, p;
                b0 = d4.x >> 8; p = atomicAdd(&hist[b0], 1);
                bucketbuf[(size_t)b0 * BUCKET_CAP + p] = make_int2(s4.x, d4.x);
                b0 = d4.y >> 8; p = atomicAdd(&hist[b0], 1);
                bucketbuf[(size_t)b0 * BUCKET_CAP + p] = make_int2(s4.y, d4.y);
                b0 = d4.z >> 8; p = atomicAdd(&hist[b0], 1);
                bucketbuf[(size_t)b0 * BUCKET_CAP + p] = make_int2(s4.z, d4.z);
                b0 = d4.w >> 8; p = atomicAdd(&hist[b0], 1);
                bucketbuf[(size_t)b0 * BUCKET_CAP + p] = make_int2(s4.w, d4.w);
            }
        }
        return;
    }

    // ---- gemm role: one 32-row tile ---------------------------------------
    __shared__ float Ws[32 * 128];    // [k][c] chunk, 16 KB
    __shared__ float Hs[32 * 36];     // [r][k] chunk, padded stride 36, 4.6 KB
    const int gemm_id = bid - bid / 9;
    if (gemm_id >= GEMM_NB) return;
    const int rbase = gemm_id * 32;

    const int rt = tid >> 5, ct = tid & 31;
    const int r0 = rt * 4, c0 = ct * 4;
    float acc[4][4];
#pragma unroll
    for (int i = 0; i < 4; ++i)
#pragma unroll
        for (int j = 0; j < 4; ++j) acc[i][j] = 0.f;

    for (int kc = 0; kc < 128; kc += 32) {
        const float4* Wg = (const float4*)(W + (size_t)kc * 128);
        float4* Ws4 = (float4*)Ws;
#pragma unroll
        for (int i = 0; i < 4; ++i)
            Ws4[i * 256 + tid] = Wg[i * 256 + tid];
        {
            int row = tid >> 3;           // 0..31
            int c4 = (tid & 7) << 2;      // 0..28
            int gr = rbase + row;
            float4 v = make_float4(0.f, 0.f, 0.f, 0.f);
            if (gr < N_NODES) v = *(const float4*)(h + (size_t)gr * 128 + kc + c4);
            *(float4*)(Hs + row * 36 + c4) = v;
        }
        __syncthreads();

#pragma unroll
        for (int k = 0; k < 32; k += 4) {
            float4 w0 = *(const float4*)(Ws + (k + 0) * 128 + c0);
            float4 w1 = *(const float4*)(Ws + (k + 1) * 128 + c0);
            float4 w2 = *(const float4*)(Ws + (k + 2) * 128 + c0);
            float4 w3 = *(const float4*)(Ws + (k + 3) * 128 + c0);
#pragma unroll
            for (int i = 0; i < 4; ++i) {
                float4 hv = *(const float4*)(Hs + (r0 + i) * 36 + k);
                acc[i][0] += hv.x * w0.x + hv.y * w1.x + hv.z * w2.x + hv.w * w3.x;
                acc[i][1] += hv.x * w0.y + hv.y * w1.y + hv.z * w2.y + hv.w * w3.y;
                acc[i][2] += hv.x * w0.z + hv.y * w1.z + hv.z * w2.z + hv.w * w3.z;
                acc[i][3] += hv.x * w0.w + hv.y * w1.w + hv.z * w2.w + hv.w * w3.w;
            }
        }
        __syncthreads();
    }

#pragma unroll
    for (int i = 0; i < 4; ++i) {
        int gr = rbase + r0 + i;
        if (gr < N_NODES) {
            float nv = norm[gr];
            half4 v;
            v.x = (_Float16)(acc[i][0] * nv);
            v.y = (_Float16)(acc[i][1] * nv);
            v.z = (_Float16)(acc[i][2] * nv);
            v.w = (_Float16)(acc[i][3] * nv);
            *(half4*)(t + (size_t)gr * 128 + c0) = v;
        }
    }
}

// -------- CSR build step 1: per-block degree sums (from norm) -------------
// Block 0 also zeroes the 196 bucket cursors for the binning pass.
__global__ __launch_bounds__(256) void scan_sums_kernel(
    const float* __restrict__ norm, int* __restrict__ bsum,
    int* __restrict__ bcur)
{
    const int tid = threadIdx.x;
    if (blockIdx.x == 0 && tid < NBUCKETS) bcur[tid] = 0;
    const int idx = blockIdx.x * 1024 + tid * 4;
    int s = 0;
    if (idx < N_NODES) {                 // 50000 % 4 == 0: group fully in-range
        float4 n = *(const float4*)(norm + idx);
        s = deg_from_norm(n.x) + deg_from_norm(n.y) +
            deg_from_norm(n.z) + deg_from_norm(n.w);
    }
#pragma unroll
    for (int d = 32; d > 0; d >>= 1) s += __shfl_down(s, d);
    __shared__ int ws[4];
    if ((tid & 63) == 0) ws[tid >> 6] = s;
    __syncthreads();
    if (tid == 0) bsum[blockIdx.x] = ws[0] + ws[1] + ws[2] + ws[3];
}

// -------- CSR build step 2: exclusive scan of 49 block sums (1 wave) ------
__global__ __launch_bounds__(64) void scan_bsum_kernel(
    const int* __restrict__ bsum, int* __restrict__ boff)
{
    const int tid = threadIdx.x;
    int v = (tid < SCAN_NB) ? bsum[tid] : 0;
    int inc = v;
#pragma unroll
    for (int d = 1; d < 64; d <<= 1) {
        int u = __shfl_up(inc, d);
        if (tid >= d) inc += u;
    }
    if (tid < SCAN_NB) boff[tid] = inc - v;   // exclusive prefix
}

// -------- CSR build step 3: block-local scan + write off ------------------
__global__ __launch_bounds__(256) void scan_write_kernel(
    const float* __restrict__ norm, const int* __restrict__ boff,
    int* __restrict__ off)
{
    const int tid = threadIdx.x;
    const int idx = blockIdx.x * 1024 + tid * 4;

    int4 v = make_int4(0, 0, 0, 0);
    if (idx < N_NODES) {
        float4 n = *(const float4*)(norm + idx);
        v.x = deg_from_norm(n.x); v.y = deg_from_norm(n.y);
        v.z = deg_from_norm(n.z); v.w = deg_from_norm(n.w);
    }
    const int s = v.x + v.y + v.z + v.w;

    const int lane = tid & 63, w = tid >> 6;
    int inc = s;
#pragma unroll
    for (int d = 1; d < 64; d <<= 1) {
        int u = __shfl_up(inc, d);
        if (lane >= d) inc += u;
    }
    __shared__ int wsum[4];
    if (lane == 63) wsum[w] = inc;
    __syncthreads();
    int woff = 0;
    for (int i = 0; i < w; ++i) woff += wsum[i];

    int o0 = boff[blockIdx.x] + woff + inc - s;
    int o1 = o0 + v.x;
    int o2 = o1 + v.y;
    int o3 = o2 + v.z;

    if (idx < N_NODES) {
        *(int4*)(off + idx) = make_int4(o0, o1, o2, o3);
    }
}

// -------- Pass 2: bucket -> esrc scatter, LDS cursors ---------------------
// One block per bucket (256 dst nodes). Cursors live in LDS (no global
// atomics); the esrc write window per block is the bucket's contiguous
// ~16 KB segment -> L2-resident, lines fully filled before writeback.
// Final cursors -> cur (aggregate's end pointers; deg-0 phantom guard).
__global__ __launch_bounds__(256) void scatter_kernel(
    const int2* __restrict__ bucketbuf, const int* __restrict__ bcur,
    const int* __restrict__ off, int* __restrict__ cur,
    int* __restrict__ esrc)
{
    const int tid = threadIdx.x;
    const int b = blockIdx.x;
    __shared__ int lcur[256];
    const int g = b * 256 + tid;
    lcur[tid] = (g < N_NODES) ? off[g] : 0;
    __syncthreads();

    const int n = bcur[b];
    const int2* buf = bucketbuf + (size_t)b * BUCKET_CAP;
    for (int i = tid; i < n; i += 256) {
        int2 p = buf[i];
        int pos = atomicAdd(&lcur[p.y & 255], 1);
        esrc[pos] = p.x;
    }
    __syncthreads();
    if (g < N_NODES) cur[g] = lcur[tid];
}

// -------- Kernel D: gather-aggregate (fp16 t) + fused finalize ------------
// 16 lanes per dst node; lane l owns halfs [8l..8l+7] (16 B load per edge).
// End pointer is cur[g] (post-scatter). Edge loop unrolled x2.
__global__ __launch_bounds__(256) void aggregate_kernel(
    const int* __restrict__ off, const int* __restrict__ cur,
    const int* __restrict__ esrc, const _Float16* __restrict__ t,
    const float* __restrict__ norm, const float* __restrict__ b,
    float* __restrict__ out)
{
    const int g = blockIdx.x * 16 + (threadIdx.x >> 4);
    if (g >= N_NODES) return;
    const int l = threadIdx.x & 15;
    const int c = l << 3;
    const int i0 = off[g], i1 = cur[g];

    float acc0[8], acc1[8];
#pragma unroll
    for (int j = 0; j < 8; ++j) { acc0[j] = 0.f; acc1[j] = 0.f; }

    int i = i0;
    for (; i + 2 <= i1; i += 2) {
        int s0 = esrc[i];
        int s1 = esrc[i + 1];
        half8 v0 = *(const half8*)(t + (size_t)s0 * 128 + c);
        half8 v1 = *(const half8*)(t + (size_t)s1 * 128 + c);
#pragma unroll
        for (int j = 0; j < 8; ++j) { acc0[j] += (float)v0[j]; acc1[j] += (float)v1[j]; }
    }
    if (i < i1) {
        int s0 = esrc[i];
        half8 v0 = *(const half8*)(t + (size_t)s0 * 128 + c);
#pragma unroll
        for (int j = 0; j < 8; ++j) acc0[j] += (float)v0[j];
    }

    const float nv = norm[g];
    const float4 b0 = *(const float4*)(b + c);
    const float4 b1 = *(const float4*)(b + c + 4);
    float4 o0 = make_float4((acc0[0] + acc1[0]) * nv + b0.x,
                            (acc0[1] + acc1[1]) * nv + b0.y,
                            (acc0[2] + acc1[2]) * nv + b0.z,
                            (acc0[3] + acc1[3]) * nv + b0.w);
    float4 o1 = make_float4((acc0[4] + acc1[4]) * nv + b1.x,
                            (acc0[5] + acc1[5]) * nv + b1.y,
                            (acc0[6] + acc1[6]) * nv + b1.z,
                            (acc0[7] + acc1[7]) * nv + b1.w);
    *(float4*)(out + (size_t)g * 128 + c) = o0;
    *(float4*)(out + (size_t)g * 128 + c + 4) = o1;
}

static inline size_t align256(size_t x) { return (x + 255) & ~(size_t)255; }

extern "C" void kernel_launch(void* const* d_in, const int* in_sizes, int n_in,
                              void* d_out, int out_size, void* d_ws, size_t ws_size,
                              hipStream_t stream)
{
    const float* h    = (const float*)d_in[0];
    const float* norm = (const float*)d_in[1];
    const float* W    = (const float*)d_in[2];
    const float* b    = (const float*)d_in[3];
    const int*   src  = (const int*)d_in[4];
    const int*   dst  = (const int*)d_in[5];
    float* out = (float*)d_out;

    // workspace layout
    char* ws = (char*)d_ws;
    size_t o = 0;
    _Float16* t = (_Float16*)(ws + o);  o = align256(o + (size_t)N_NODES * 128 * 2);
    int* off = (int*)(ws + o);          o = align256(o + (size_t)N_NODES * 4);
    int* cur = (int*)(ws + o);          o = align256(o + (size_t)N_NODES * 4);
    int* esrc = (int*)(ws + o);         o = align256(o + ((size_t)N_EDGES + 1024) * 4);
    int* bsum = (int*)(ws + o);         o = align256(o + (size_t)SCAN_NB * 4);
    int* boff = (int*)(ws + o);         o = align256(o + (size_t)SCAN_NB * 4);
    int* bcur = (int*)(ws + o);         o = align256(o + (size_t)NBUCKETS * 4);
    int2* bucketbuf = (int2*)(ws + o);  o = align256(o + (size_t)NBUCKETS * BUCKET_CAP * 8);

    scan_sums_kernel<<<SCAN_NB, 256, 0, stream>>>(norm, bsum, bcur);
    scan_bsum_kernel<<<1, 64, 0, stream>>>(bsum, boff);
    scan_write_kernel<<<SCAN_NB, 256, 0, stream>>>(norm, boff, off);
    fused_gemm_bin_kernel<<<FUSED_NB, 256, 0, stream>>>(h, norm, W, t,
                                                        src, dst, bcur, bucketbuf);
    scatter_kernel<<<NBUCKETS, 256, 0, stream>>>(bucketbuf, bcur, off, cur, esrc);
    aggregate_kernel<<<(N_NODES + 15) / 16, 256, 0, stream>>>(off, cur, esrc, t, norm, b, out);
}